// Round 7
// baseline (340.206 us; speedup 1.0000x reference)
//
#include <hip/hip_runtime.h>
#include <hip/hip_fp16.h>

// GNN mean-aggregate + dual GEMM. N=50000, E=1.6M, DIM=128, fp32 in/out.
// Pipeline (5 launches): k_prep (pack W + init cursors + x->f16 xt tiles +
// x-half of A) -> k_bin -> k_csort -> k_gather (XCD-pinned column tiles)
// -> MFMA GEMM.
// R1: 4-deep pipeline (NEUTRAL - not latency-bound).
// R2: full-width 1-wave/node gather: 83us, HBM-side 3.6 TB/s (random-64B
//     ceiling), FETCH 284MB.
// R3/R4: footprint chasing without XCD awareness - tiles ran concurrently
//     on every XCD (12.8MB > 4MB/XCD L2) -> thrash, worse.
// R5: serialized tile passes: L2-resident but 4x pass overhead, worse.
// R6: 5-launch cleanup, 250us total. Gather = HBM-random-BW bound.
// R7: tile = blockIdx.x & 3 pins ONE 3.2MB tile per XCD (bid%8=XCD
//     round-robin, T1-validated): per-XCD L2 working set fits -> row
//     reads L2-hit, single launch, all tiles concurrent but disjoint.
//     Inner body = R4's treeless gather (VALU 10%). Non-temporal nbr
//     loads keep the stream from evicting the tile.

constexpr int DIM    = 128;
constexpr int NBMAX  = 512;    // coarse buckets (node>>7); N=50000 -> 391
constexpr int EPB    = 2048;   // edges per binning block (256 thr x 8)
constexpr int CAP    = 9216;   // entries per bucket (E[cnt]=8184, ~11 sigma)
constexpr int NTILES = 4;      // 32-col f16 tiles

typedef _Float16 half8 __attribute__((ext_vector_type(8)));
typedef __attribute__((ext_vector_type(4))) float f32x4;

__device__ __forceinline__ unsigned hadd2u(unsigned a, unsigned b) {
    __half2 ha = *reinterpret_cast<__half2*>(&a);
    __half2 hb = *reinterpret_cast<__half2*>(&b);
    __half2 r  = __hadd2(ha, hb);
    return *reinterpret_cast<unsigned*>(&r);
}
__device__ __forceinline__ unsigned hmul2u(unsigned a, __half2 s) {
    __half2 ha = *reinterpret_cast<__half2*>(&a);
    __half2 r  = __hmul2(ha, s);
    return *reinterpret_cast<unsigned*>(&r);
}
__device__ __forceinline__ unsigned packf16(float x, float y) {
    __half2 h = __floats2half2_rn(x, y);
    return *reinterpret_cast<unsigned*>(&h);
}
__device__ __forceinline__ uint4 hadd2q(uint4 a, uint4 b) {
    uint4 r;
    r.x = hadd2u(a.x, b.x);
    r.y = hadd2u(a.y, b.y);
    r.z = hadd2u(a.z, b.z);
    r.w = hadd2u(a.w, b.w);
    return r;
}

// --- K0: fused prep. (a) bucket cursors; (b) pack [Wn;Ws] -> Bp f16
// B-fragments; (c) x fp32 -> f16: xt column tiles AND x-half of A. ---
__global__ __launch_bounds__(256) void k_prep(
    const float* __restrict__ Wn, const float* __restrict__ Ws,
    const float* __restrict__ x,
    unsigned short* __restrict__ Bp, int* __restrict__ bucket_cur,
    unsigned* __restrict__ xt, unsigned* __restrict__ abf,
    int nb, int n_nodes)
{
    int i = blockIdx.x * 256 + threadIdx.x;
    if (i < nb) bucket_cur[i] = i * CAP;
    if (i < 8 * 128 * 4 * 8) {
        int j    = i & 7;
        int quad = (i >> 3) & 3;
        int n    = (i >> 5) & 127;
        int kb   = i >> 12;
        int k = kb * 32 + quad * 8 + j;
        float v = (k < 128) ? Wn[k * 128 + n] : Ws[(k - 128) * 128 + n];
        __half h = __float2half_rn(v);
        Bp[i] = *reinterpret_cast<unsigned short*>(&h);
    }
    if (i < n_nodes * 64) {
        int n = i >> 6;
        int u = i & 63;
        float2 f = ((const float2*)(x + (size_t)n * DIM))[u];
        unsigned pk = packf16(f.x, f.y);
        abf[(size_t)n * 128 + 64 + u] = pk;
        int t  = u >> 4;
        int uu = u & 15;
        xt[(size_t)t * n_nodes * 16 + (size_t)n * 16 + uu] = pk;
    }
}

// --- K1: bin endpoints into fixed-cap buckets.
// Per-wave LDS histogram -> global frontier alloc (1 atomic-return per
// (block,bucket)) -> block-local LDS counting sort -> coalesced writeback. ---
__global__ __launch_bounds__(256) void k_bin(
    const int* __restrict__ edge, int* __restrict__ bucket_cur,
    unsigned* __restrict__ entries, int n_edges, int nb)
{
    __shared__ int lh[4][NBMAX];
    __shared__ int Lb[NBMAX];
    __shared__ int gb[NBMAX];
    __shared__ int sc[512];
    __shared__ unsigned sorted[2 * EPB];
    __shared__ int      gaddr[2 * EPB];

    int t = threadIdx.x;
    int w = t >> 6;
    for (int i = t; i < 4 * NBMAX; i += 256) ((int*)lh)[i] = 0;
    __syncthreads();

    int e0 = blockIdx.x * EPB;
    int2 ev[8];
    #pragma unroll
    for (int k = 0; k < 8; k++) {
        int idx = e0 + k * 256 + t;
        if (idx < n_edges) {
            ev[k] = ((const int2*)edge)[idx];
            atomicAdd(&lh[w][ev[k].x >> 7], 1);
            atomicAdd(&lh[w][ev[k].y >> 7], 1);
        } else {
            ev[k].x = -1;
        }
    }
    __syncthreads();

    for (int i = t; i < 512; i += 256)
        sc[i] = (i < nb) ? (lh[0][i] + lh[1][i] + lh[2][i] + lh[3][i]) : 0;
    __syncthreads();
    for (int d = 1; d < 512; d <<= 1) {
        int v0 = 0, v1 = 0;
        int i0 = t, i1 = t + 256;
        if (i0 >= d) v0 = sc[i0 - d];
        if (i1 >= d) v1 = sc[i1 - d];
        __syncthreads();
        if (i0 >= d) sc[i0] += v0;
        if (i1 >= d) sc[i1] += v1;
        __syncthreads();
    }
    for (int i = t; i < nb; i += 256) {
        int c0 = lh[0][i], c1 = lh[1][i], c2 = lh[2][i], c3 = lh[3][i];
        int tot = c0 + c1 + c2 + c3;
        int L = sc[i] - tot;
        Lb[i] = L;
        gb[i] = tot ? atomicAdd(&bucket_cur[i], tot) : 0;
        lh[0][i] = L;
        lh[1][i] = L + c0;
        lh[2][i] = L + c0 + c1;
        lh[3][i] = L + c0 + c1 + c2;
    }
    __syncthreads();

    #pragma unroll
    for (int k = 0; k < 8; k++) {
        int a = ev[k].x;
        if (a < 0) continue;
        int b = ev[k].y;
        int ba = a >> 7, bb = b >> 7;
        int sa = atomicAdd(&lh[w][ba], 1);
        sorted[sa] = ((unsigned)(a & 127) << 16) | (unsigned)b;
        gaddr[sa]  = gb[ba] + sa - Lb[ba];
        int sb = atomicAdd(&lh[w][bb], 1);
        sorted[sb] = ((unsigned)(b & 127) << 16) | (unsigned)a;
        gaddr[sb]  = gb[bb] + sb - Lb[bb];
    }
    __syncthreads();

    int cntb = sc[511];
    for (int p = t; p < cntb; p += 256)
        entries[gaddr[p]] = sorted[p];
}

// --- K2: per-bucket counting sort, 512 threads, 8-way privatized cursors ---
__global__ __launch_bounds__(512) void k_csort(
    const unsigned* __restrict__ entries, const int* __restrict__ bucket_cur,
    unsigned* __restrict__ offsets, int* __restrict__ degs,
    unsigned short* __restrict__ nbr, int n_nodes)
{
    int b    = blockIdx.x;
    int base = b * CAP;
    int cnt  = bucket_cur[b] - base;
    __shared__ int lh[8][128];
    __shared__ int scn[128];
    int t = threadIdx.x;
    int w = t >> 6;
    for (int i = t; i < 8 * 128; i += 512) ((int*)lh)[i] = 0;
    __syncthreads();
    for (int i = t; i < cnt; i += 512)
        atomicAdd(&lh[w][entries[base + i] >> 16], 1);
    __syncthreads();
    int tot = 0;
    if (t < 128) {
        #pragma unroll
        for (int ww = 0; ww < 8; ww++) tot += lh[ww][t];
        scn[t] = tot;
    }
    __syncthreads();
    for (int d = 1; d < 128; d <<= 1) {
        int u = (t >= d && t < 128) ? scn[t - d] : 0;
        __syncthreads();
        if (t >= d && t < 128) scn[t] += u;
        __syncthreads();
    }
    if (t < 128) {
        int excl = scn[t] - tot;
        int node = (b << 7) + t;
        if (node < n_nodes) {
            offsets[node] = (unsigned)(base + excl);
            degs[node]    = tot;
        }
        int run = excl;
        #pragma unroll
        for (int ww = 0; ww < 8; ww++) { int c = lh[ww][t]; lh[ww][t] = run; run += c; }
    }
    __syncthreads();
    for (int i = t; i < cnt; i += 512) {
        unsigned e = entries[base + i];
        int slot = atomicAdd(&lh[w][e >> 16], 1);
        nbr[base + slot] = (unsigned short)(e & 0xFFFFu);
    }
}

// --- K4 (R7): XCD-pinned treeless tiled gather + mean.
// tile = bid & 3 -> with bid%8=XCD round-robin, each XCD touches exactly
// one 3.2MB tile (fits 4MB L2). 64 nodes/block, 16 nodes/wave, 4-lane
// group per node streams entries with 4 depth-slot accumulators; 2-level
// in-register merge; no cross-lane reduce. Non-temporal nbr loads. ---
__global__ __launch_bounds__(256) void k_gather(
    const unsigned* __restrict__ xt,        // [NTILES][n_nodes][16] uints
    const unsigned* __restrict__ offsets,
    const int* __restrict__ degs,
    const unsigned short* __restrict__ nbr,
    unsigned* __restrict__ abf, int n_nodes)
{
    int bid  = blockIdx.x;
    int tile = bid & 3;
    int nblk = bid >> 2;
    int wave = threadIdx.x >> 6;
    int lane = threadIdx.x & 63;
    int grp  = lane >> 2;          // 0..15: node within the wave
    int u    = lane & 3;           // uint4 within the 64B row-tile
    int node = nblk * 64 + wave * 16 + grp;
    const uint4* xt_tile = (const uint4*)(xt + (size_t)tile * n_nodes * 16);
    bool valid = node < n_nodes;
    int base = 0, deg = 0;
    if (valid) { base = (int)offsets[node]; deg = degs[node]; }
    int end = base + deg;

    uint4 s0 = {0u, 0u, 0u, 0u};
    uint4 s1 = s0, s2 = s0, s3 = s0;

    int i = base;
    for (; i + 3 < end; i += 4) {
        int v0 = __builtin_nontemporal_load(&nbr[i]);
        int v1 = __builtin_nontemporal_load(&nbr[i + 1]);
        int v2 = __builtin_nontemporal_load(&nbr[i + 2]);
        int v3 = __builtin_nontemporal_load(&nbr[i + 3]);
        uint4 w0 = xt_tile[v0 * 4 + u];
        uint4 w1 = xt_tile[v1 * 4 + u];
        uint4 w2 = xt_tile[v2 * 4 + u];
        uint4 w3 = xt_tile[v3 * 4 + u];
        s0 = hadd2q(s0, w0);
        s1 = hadd2q(s1, w1);
        s2 = hadd2q(s2, w2);
        s3 = hadd2q(s3, w3);
    }
    for (; i < end; i++) {
        int v = __builtin_nontemporal_load(&nbr[i]);
        s0 = hadd2q(s0, xt_tile[v * 4 + u]);
    }

    uint4 m = hadd2q(hadd2q(s0, s1), hadd2q(s2, s3));

    if (valid) {
        float inv = 1.0f / fmaxf((float)deg, 1.0f);
        __half2 iv = __float2half2_rn(inv);
        uint4 o;
        o.x = hmul2u(m.x, iv);
        o.y = hmul2u(m.y, iv);
        o.z = hmul2u(m.z, iv);
        o.w = hmul2u(m.w, iv);
        ((uint4*)(abf + (size_t)node * 128 + tile * 16))[u] = o;
    }
}

// --- K5: MFMA f16 GEMM in-place on d_out. A = abf [n][256] f16. ---
__global__ __launch_bounds__(256) void k_mfma_gemm(
    const unsigned short* __restrict__ abf,
    const unsigned short* __restrict__ Bp,
    const float* __restrict__ bias,
    float* __restrict__ out, int n_nodes)
{
    int wave = threadIdx.x >> 6;
    int lane = threadIdx.x & 63;
    int quad = lane >> 4;
    int l16  = lane & 15;
    int row0 = blockIdx.x * 64 + wave * 16;

    int arow = min(row0 + l16, n_nodes - 1);
    const unsigned short* arp = abf + (size_t)arow * 256 + quad * 8;
    half8 afrag[8];
    #pragma unroll
    for (int kb = 0; kb < 8; kb++)
        afrag[kb] = *((const half8*)(arp + kb * 32));

    f32x4 acc[8];
    #pragma unroll
    for (int f = 0; f < 8; f++) acc[f] = (f32x4){0.f, 0.f, 0.f, 0.f};

    #pragma unroll
    for (int kb = 0; kb < 8; kb++) {
        #pragma unroll
        for (int f = 0; f < 8; f++) {
            int n = f * 16 + l16;
            half8 bfrag = *((const half8*)(Bp + (((size_t)kb * 128 + n) * 4 + quad) * 8));
            acc[f] = __builtin_amdgcn_mfma_f32_16x16x32_f16(afrag[kb], bfrag, acc[f], 0, 0, 0);
        }
    }

    #pragma unroll
    for (int f = 0; f < 8; f++) {
        float bv = bias[f * 16 + l16];
        #pragma unroll
        for (int r = 0; r < 4; r++) {
            int row = row0 + quad * 4 + r;
            if (row < n_nodes)
                out[(size_t)row * DIM + f * 16 + l16] = acc[f][r] + bv;
        }
    }
}

extern "C" void kernel_launch(void* const* d_in, const int* in_sizes, int n_in,
                              void* d_out, int out_size, void* d_ws, size_t ws_size,
                              hipStream_t stream) {
    const float* x    = (const float*)d_in[0];
    const int*   edge = (const int*)  d_in[1];
    const float* Wn   = (const float*)d_in[2];
    const float* Ws   = (const float*)d_in[3];
    const float* b    = (const float*)d_in[4];
    float* out = (float*)d_out;

    const int n_nodes = in_sizes[0] / DIM;   // 50000
    const int n_edges = in_sizes[1] / 2;     // 1600000
    const int nb = (n_nodes + 127) >> 7;     // 391

    // ws: entries[nb*CAP] u32 | nbr[nb*CAP] u16 | offsets[N] u32 | degs[N] |
    //     bucket_cur[nb] | Bp (64KB) | xt (12.8MB, NOT aliased - entries
    //     live until csort, xt written by prep before bin).
    unsigned* entries      = (unsigned*)d_ws;
    unsigned short* nbr    = (unsigned short*)(entries + (size_t)nb * CAP);
    unsigned* offsets      = (unsigned*)(nbr + (size_t)nb * CAP);
    int* degs              = (int*)(offsets + n_nodes);
    int* bucket_cur        = degs + n_nodes;
    unsigned short* Bp     = (unsigned short*)((((size_t)(bucket_cur + nb)) + 63) & ~(size_t)63);
    unsigned* xt           = (unsigned*)(Bp + 8 * 128 * 4 * 8);
    unsigned* abf          = (unsigned*)d_out;

    const int nprep = n_nodes * 64;          // 3.2M threads covers all 3 jobs
    k_prep<<<(nprep + 255) / 256, 256, 0, stream>>>(Wn, Ws, x, Bp, bucket_cur,
                                                    xt, abf, nb, n_nodes);

    const int bb = (n_edges + EPB - 1) / EPB;   // 782
    k_bin<<<bb, 256, 0, stream>>>(edge, bucket_cur, entries, n_edges, nb);
    k_csort<<<nb, 512, 0, stream>>>(entries, bucket_cur, offsets, degs, nbr, n_nodes);

    const int gblocks = ((n_nodes + 63) / 64) * NTILES;   // 782*4 = 3128
    k_gather<<<gblocks, 256, 0, stream>>>(xt, offsets, degs, nbr, abf, n_nodes);

    const int mb = (n_nodes + 63) / 64;
    k_mfma_gemm<<<mb, 256, 0, stream>>>((const unsigned short*)abf, Bp, b,
                                        out, n_nodes);
}

// Round 8
// 272.356 us; speedup vs baseline: 1.2491x; 1.2491x over previous
//
#include <hip/hip_runtime.h>
#include <hip/hip_fp16.h>

// GNN mean-aggregate + dual GEMM. N=50000, E=1.6M, DIM=128, fp32 in/out.
// Pipeline (5 launches): k_prep (pack W + cursors + x->f16 xt tiles +
// x-half of A) -> k_bin -> k_csort -> k_gather (persistent XCD-pinned
// column tiles) -> MFMA GEMM.
// R2: full-width gather: 83us = L3-random-access bound (3.6 TB/s).
// R5: serialized L2-resident tile passes: ~8.5 TB/s effective per pass
//     (~24us) - proves L2-resident is 3.5x faster - but 4x pass
//     overhead ate it.
// R7: XCD pinning with 3128 blocks FAILED: only ~2048 blocks resident,
//     tail blocks land on wrong XCD -> 2 tiles/L2 -> thrash. Plus NT
//     index loads made the dependent row loads latency-bound (VALU 8%).
// R8: persistent resident grid (1568 blocks <= capacity): bid%8=XCD
//     holds for the whole kernel. tile=(bid&7)&3 -> one 3.2MB tile per
//     XCD L2. Wave-level grid-stride over 16-node chunks (max 2/worker,
//     balanced). Plain nbr loads. Body = R4's treeless loop (proven).

constexpr int DIM    = 128;
constexpr int NBMAX  = 512;    // coarse buckets (node>>7); N=50000 -> 391
constexpr int EPB    = 2048;   // edges per binning block (256 thr x 8)
constexpr int CAP    = 9216;   // entries per bucket (E[cnt]=8184, ~11 sigma)
constexpr int NTILES = 4;      // 32-col f16 tiles

typedef _Float16 half8 __attribute__((ext_vector_type(8)));
typedef __attribute__((ext_vector_type(4))) float f32x4;

__device__ __forceinline__ unsigned hadd2u(unsigned a, unsigned b) {
    __half2 ha = *reinterpret_cast<__half2*>(&a);
    __half2 hb = *reinterpret_cast<__half2*>(&b);
    __half2 r  = __hadd2(ha, hb);
    return *reinterpret_cast<unsigned*>(&r);
}
__device__ __forceinline__ unsigned hmul2u(unsigned a, __half2 s) {
    __half2 ha = *reinterpret_cast<__half2*>(&a);
    __half2 r  = __hmul2(ha, s);
    return *reinterpret_cast<unsigned*>(&r);
}
__device__ __forceinline__ unsigned packf16(float x, float y) {
    __half2 h = __floats2half2_rn(x, y);
    return *reinterpret_cast<unsigned*>(&h);
}
__device__ __forceinline__ uint4 hadd2q(uint4 a, uint4 b) {
    uint4 r;
    r.x = hadd2u(a.x, b.x);
    r.y = hadd2u(a.y, b.y);
    r.z = hadd2u(a.z, b.z);
    r.w = hadd2u(a.w, b.w);
    return r;
}

// --- K0: fused prep. (a) bucket cursors; (b) pack [Wn;Ws] -> Bp f16
// B-fragments; (c) x fp32 -> f16: xt column tiles AND x-half of A. ---
__global__ __launch_bounds__(256) void k_prep(
    const float* __restrict__ Wn, const float* __restrict__ Ws,
    const float* __restrict__ x,
    unsigned short* __restrict__ Bp, int* __restrict__ bucket_cur,
    unsigned* __restrict__ xt, unsigned* __restrict__ abf,
    int nb, int n_nodes)
{
    int i = blockIdx.x * 256 + threadIdx.x;
    if (i < nb) bucket_cur[i] = i * CAP;
    if (i < 8 * 128 * 4 * 8) {
        int j    = i & 7;
        int quad = (i >> 3) & 3;
        int n    = (i >> 5) & 127;
        int kb   = i >> 12;
        int k = kb * 32 + quad * 8 + j;
        float v = (k < 128) ? Wn[k * 128 + n] : Ws[(k - 128) * 128 + n];
        __half h = __float2half_rn(v);
        Bp[i] = *reinterpret_cast<unsigned short*>(&h);
    }
    if (i < n_nodes * 64) {
        int n = i >> 6;
        int u = i & 63;
        float2 f = ((const float2*)(x + (size_t)n * DIM))[u];
        unsigned pk = packf16(f.x, f.y);
        abf[(size_t)n * 128 + 64 + u] = pk;
        int t  = u >> 4;
        int uu = u & 15;
        xt[(size_t)t * n_nodes * 16 + (size_t)n * 16 + uu] = pk;
    }
}

// --- K1: bin endpoints into fixed-cap buckets.
// Per-wave LDS histogram -> global frontier alloc (1 atomic-return per
// (block,bucket)) -> block-local LDS counting sort -> coalesced writeback. ---
__global__ __launch_bounds__(256) void k_bin(
    const int* __restrict__ edge, int* __restrict__ bucket_cur,
    unsigned* __restrict__ entries, int n_edges, int nb)
{
    __shared__ int lh[4][NBMAX];
    __shared__ int Lb[NBMAX];
    __shared__ int gb[NBMAX];
    __shared__ int sc[512];
    __shared__ unsigned sorted[2 * EPB];
    __shared__ int      gaddr[2 * EPB];

    int t = threadIdx.x;
    int w = t >> 6;
    for (int i = t; i < 4 * NBMAX; i += 256) ((int*)lh)[i] = 0;
    __syncthreads();

    int e0 = blockIdx.x * EPB;
    int2 ev[8];
    #pragma unroll
    for (int k = 0; k < 8; k++) {
        int idx = e0 + k * 256 + t;
        if (idx < n_edges) {
            ev[k] = ((const int2*)edge)[idx];
            atomicAdd(&lh[w][ev[k].x >> 7], 1);
            atomicAdd(&lh[w][ev[k].y >> 7], 1);
        } else {
            ev[k].x = -1;
        }
    }
    __syncthreads();

    for (int i = t; i < 512; i += 256)
        sc[i] = (i < nb) ? (lh[0][i] + lh[1][i] + lh[2][i] + lh[3][i]) : 0;
    __syncthreads();
    for (int d = 1; d < 512; d <<= 1) {
        int v0 = 0, v1 = 0;
        int i0 = t, i1 = t + 256;
        if (i0 >= d) v0 = sc[i0 - d];
        if (i1 >= d) v1 = sc[i1 - d];
        __syncthreads();
        if (i0 >= d) sc[i0] += v0;
        if (i1 >= d) sc[i1] += v1;
        __syncthreads();
    }
    for (int i = t; i < nb; i += 256) {
        int c0 = lh[0][i], c1 = lh[1][i], c2 = lh[2][i], c3 = lh[3][i];
        int tot = c0 + c1 + c2 + c3;
        int L = sc[i] - tot;
        Lb[i] = L;
        gb[i] = tot ? atomicAdd(&bucket_cur[i], tot) : 0;
        lh[0][i] = L;
        lh[1][i] = L + c0;
        lh[2][i] = L + c0 + c1;
        lh[3][i] = L + c0 + c1 + c2;
    }
    __syncthreads();

    #pragma unroll
    for (int k = 0; k < 8; k++) {
        int a = ev[k].x;
        if (a < 0) continue;
        int b = ev[k].y;
        int ba = a >> 7, bb = b >> 7;
        int sa = atomicAdd(&lh[w][ba], 1);
        sorted[sa] = ((unsigned)(a & 127) << 16) | (unsigned)b;
        gaddr[sa]  = gb[ba] + sa - Lb[ba];
        int sb = atomicAdd(&lh[w][bb], 1);
        sorted[sb] = ((unsigned)(b & 127) << 16) | (unsigned)a;
        gaddr[sb]  = gb[bb] + sb - Lb[bb];
    }
    __syncthreads();

    int cntb = sc[511];
    for (int p = t; p < cntb; p += 256)
        entries[gaddr[p]] = sorted[p];
}

// --- K2: per-bucket counting sort, 512 threads, 8-way privatized cursors ---
__global__ __launch_bounds__(512) void k_csort(
    const unsigned* __restrict__ entries, const int* __restrict__ bucket_cur,
    unsigned* __restrict__ offsets, int* __restrict__ degs,
    unsigned short* __restrict__ nbr, int n_nodes)
{
    int b    = blockIdx.x;
    int base = b * CAP;
    int cnt  = bucket_cur[b] - base;
    __shared__ int lh[8][128];
    __shared__ int scn[128];
    int t = threadIdx.x;
    int w = t >> 6;
    for (int i = t; i < 8 * 128; i += 512) ((int*)lh)[i] = 0;
    __syncthreads();
    for (int i = t; i < cnt; i += 512)
        atomicAdd(&lh[w][entries[base + i] >> 16], 1);
    __syncthreads();
    int tot = 0;
    if (t < 128) {
        #pragma unroll
        for (int ww = 0; ww < 8; ww++) tot += lh[ww][t];
        scn[t] = tot;
    }
    __syncthreads();
    for (int d = 1; d < 128; d <<= 1) {
        int u = (t >= d && t < 128) ? scn[t - d] : 0;
        __syncthreads();
        if (t >= d && t < 128) scn[t] += u;
        __syncthreads();
    }
    if (t < 128) {
        int excl = scn[t] - tot;
        int node = (b << 7) + t;
        if (node < n_nodes) {
            offsets[node] = (unsigned)(base + excl);
            degs[node]    = tot;
        }
        int run = excl;
        #pragma unroll
        for (int ww = 0; ww < 8; ww++) { int c = lh[ww][t]; lh[ww][t] = run; run += c; }
    }
    __syncthreads();
    for (int i = t; i < cnt; i += 512) {
        unsigned e = entries[base + i];
        int slot = atomicAdd(&lh[w][e >> 16], 1);
        nbr[base + slot] = (unsigned short)(e & 0xFFFFu);
    }
}

// --- K4 (R8): persistent XCD-pinned treeless tiled gather + mean.
// Grid fully resident (<=2048 blocks) so bid%8=XCD holds permanently.
// tile=(bid&7)&3: each XCD touches exactly one 3.2MB tile (fits 4MB L2).
// Wave-level grid-stride over 16-node chunks; 4-lane group per node
// streams entries with 4 depth-slot accumulators; 2-level in-register
// merge; plain (cached) nbr loads. ---
__global__ __launch_bounds__(256) void k_gather(
    const unsigned* __restrict__ xt,        // [NTILES][n_nodes][16] uints
    const unsigned* __restrict__ offsets,
    const int* __restrict__ degs,
    const unsigned short* __restrict__ nbr,
    unsigned* __restrict__ abf, int n_nodes)
{
    int bid  = blockIdx.x;
    int xcd  = bid & 7;
    int tile = xcd & 3;
    int wave = threadIdx.x >> 6;
    int lane = threadIdx.x & 63;
    int grp  = lane >> 2;          // 0..15: node within the chunk
    int u    = lane & 3;           // uint4 within the 64B row-tile
    const uint4* xt_tile = (const uint4*)(xt + (size_t)tile * n_nodes * 16);

    int bpx      = (int)gridDim.x >> 3;                     // blocks per XCD
    int wwid     = (((xcd >> 2) * bpx) + (bid >> 3)) * 4 + wave; // worker in tile
    int nworkers = bpx * 8;                                  // 2 XCDs * bpx * 4 waves
    int nchunks  = (n_nodes + 15) >> 4;

    for (int chunk = wwid; chunk < nchunks; chunk += nworkers) {
        int node = chunk * 16 + grp;
        bool valid = node < n_nodes;
        int base = 0, deg = 0;
        if (valid) { base = (int)offsets[node]; deg = degs[node]; }
        int end = base + deg;

        uint4 s0 = {0u, 0u, 0u, 0u};
        uint4 s1 = s0, s2 = s0, s3 = s0;

        int i = base;
        for (; i + 3 < end; i += 4) {
            int v0 = nbr[i];
            int v1 = nbr[i + 1];
            int v2 = nbr[i + 2];
            int v3 = nbr[i + 3];
            uint4 w0 = xt_tile[v0 * 4 + u];
            uint4 w1 = xt_tile[v1 * 4 + u];
            uint4 w2 = xt_tile[v2 * 4 + u];
            uint4 w3 = xt_tile[v3 * 4 + u];
            s0 = hadd2q(s0, w0);
            s1 = hadd2q(s1, w1);
            s2 = hadd2q(s2, w2);
            s3 = hadd2q(s3, w3);
        }
        for (; i < end; i++) {
            int v = nbr[i];
            s0 = hadd2q(s0, xt_tile[v * 4 + u]);
        }

        uint4 m = hadd2q(hadd2q(s0, s1), hadd2q(s2, s3));

        if (valid) {
            float inv = 1.0f / fmaxf((float)deg, 1.0f);
            __half2 iv = __float2half2_rn(inv);
            uint4 o;
            o.x = hmul2u(m.x, iv);
            o.y = hmul2u(m.y, iv);
            o.z = hmul2u(m.z, iv);
            o.w = hmul2u(m.w, iv);
            ((uint4*)(abf + (size_t)node * 128 + tile * 16))[u] = o;
        }
    }
}

// --- K5: MFMA f16 GEMM in-place on d_out. A = abf [n][256] f16. ---
__global__ __launch_bounds__(256) void k_mfma_gemm(
    const unsigned short* __restrict__ abf,
    const unsigned short* __restrict__ Bp,
    const float* __restrict__ bias,
    float* __restrict__ out, int n_nodes)
{
    int wave = threadIdx.x >> 6;
    int lane = threadIdx.x & 63;
    int quad = lane >> 4;
    int l16  = lane & 15;
    int row0 = blockIdx.x * 64 + wave * 16;

    int arow = min(row0 + l16, n_nodes - 1);
    const unsigned short* arp = abf + (size_t)arow * 256 + quad * 8;
    half8 afrag[8];
    #pragma unroll
    for (int kb = 0; kb < 8; kb++)
        afrag[kb] = *((const half8*)(arp + kb * 32));

    f32x4 acc[8];
    #pragma unroll
    for (int f = 0; f < 8; f++) acc[f] = (f32x4){0.f, 0.f, 0.f, 0.f};

    #pragma unroll
    for (int kb = 0; kb < 8; kb++) {
        #pragma unroll
        for (int f = 0; f < 8; f++) {
            int n = f * 16 + l16;
            half8 bfrag = *((const half8*)(Bp + (((size_t)kb * 128 + n) * 4 + quad) * 8));
            acc[f] = __builtin_amdgcn_mfma_f32_16x16x32_f16(afrag[kb], bfrag, acc[f], 0, 0, 0);
        }
    }

    #pragma unroll
    for (int f = 0; f < 8; f++) {
        float bv = bias[f * 16 + l16];
        #pragma unroll
        for (int r = 0; r < 4; r++) {
            int row = row0 + quad * 4 + r;
            if (row < n_nodes)
                out[(size_t)row * DIM + f * 16 + l16] = acc[f][r] + bv;
        }
    }
}

extern "C" void kernel_launch(void* const* d_in, const int* in_sizes, int n_in,
                              void* d_out, int out_size, void* d_ws, size_t ws_size,
                              hipStream_t stream) {
    const float* x    = (const float*)d_in[0];
    const int*   edge = (const int*)  d_in[1];
    const float* Wn   = (const float*)d_in[2];
    const float* Ws   = (const float*)d_in[3];
    const float* b    = (const float*)d_in[4];
    float* out = (float*)d_out;

    const int n_nodes = in_sizes[0] / DIM;   // 50000
    const int n_edges = in_sizes[1] / 2;     // 1600000
    const int nb = (n_nodes + 127) >> 7;     // 391

    // ws: entries[nb*CAP] u32 | nbr[nb*CAP] u16 | offsets[N] u32 | degs[N] |
    //     bucket_cur[nb] | Bp (64KB) | xt (12.8MB).
    unsigned* entries      = (unsigned*)d_ws;
    unsigned short* nbr    = (unsigned short*)(entries + (size_t)nb * CAP);
    unsigned* offsets      = (unsigned*)(nbr + (size_t)nb * CAP);
    int* degs              = (int*)(offsets + n_nodes);
    int* bucket_cur        = degs + n_nodes;
    unsigned short* Bp     = (unsigned short*)((((size_t)(bucket_cur + nb)) + 63) & ~(size_t)63);
    unsigned* xt           = (unsigned*)(Bp + 8 * 128 * 4 * 8);
    unsigned* abf          = (unsigned*)d_out;

    const int nprep = n_nodes * 64;          // 3.2M threads covers all 3 jobs
    k_prep<<<(nprep + 255) / 256, 256, 0, stream>>>(Wn, Ws, x, Bp, bucket_cur,
                                                    xt, abf, nb, n_nodes);

    const int bb = (n_edges + EPB - 1) / EPB;   // 782
    k_bin<<<bb, 256, 0, stream>>>(edge, bucket_cur, entries, n_edges, nb);
    k_csort<<<nb, 512, 0, stream>>>(entries, bucket_cur, offsets, degs, nbr, n_nodes);

    // persistent resident grid: 1568 blocks (196/XCD), multiple of 8,
    // <= 2048 residency capacity (VGPR~32, no LDS) -> bid%8=XCD stable.
    // Per tile: 2 XCDs * 196 blocks * 4 waves = 1568 wave-workers over
    // 3125 chunks -> max 2 chunks/worker (balanced).
    k_gather<<<1568, 256, 0, stream>>>(xt, offsets, degs, nbr, abf, n_nodes);

    const int mb = (n_nodes + 63) / 64;
    k_mfma_gemm<<<mb, 256, 0, stream>>>((const unsigned short*)abf, Bp, b,
                                        out, n_nodes);
}